// Round 1
// baseline (274.924 us; speedup 1.0000x reference)
//
#include <hip/hip_runtime.h>

#define NY_ 496
#define NX_ 432
#define C_  64
#define PLANE_ (NY_ * NX_)   // 214272

// ---------------------------------------------------------------------------
// Pass 1: init index map to -1 (vectorized int4, grid-stride)
// ---------------------------------------------------------------------------
__global__ void init_idx_kernel(int* __restrict__ idx, int n4) {
    int t = blockIdx.x * blockDim.x + threadIdx.x;
    int stride = gridDim.x * blockDim.x;
    const int4 m = make_int4(-1, -1, -1, -1);
    for (int i = t; i < n4; i += stride) {
        reinterpret_cast<int4*>(idx)[i] = m;
    }
}

// ---------------------------------------------------------------------------
// Pass 2: scatter pillar index into the map (tiny: P 4-byte writes)
// coords row = [sample, z, y, x]
// ---------------------------------------------------------------------------
__global__ void scatter_idx_kernel(const int* __restrict__ coords,
                                   int* __restrict__ idx, int P) {
    int p = blockIdx.x * blockDim.x + threadIdx.x;
    if (p >= P) return;
    int4 c = reinterpret_cast<const int4*>(coords)[p];
    int lin = c.x * PLANE_ + c.z * NX_ + c.w;
    idx[lin] = p;
}

// ---------------------------------------------------------------------------
// Pass 3: write the whole canvas coalesced. Each thread owns 4 consecutive
// (y,x) cells; loops over 64 channels writing float4. Empty quads (the vast
// majority) take the pure-zero fast path.
// ---------------------------------------------------------------------------
__global__ void fill_out_kernel(const float* __restrict__ feats,
                                const int* __restrict__ idx,
                                float* __restrict__ out, int ncell4) {
    int t = blockIdx.x * blockDim.x + threadIdx.x;
    if (t >= ncell4) return;

    int4 p4 = reinterpret_cast<const int4*>(idx)[t];
    int cell0 = t << 2;                  // first of 4 cells (same sample: PLANE_ % 4 == 0)
    int b = cell0 / PLANE_;
    int rem = cell0 - b * PLANE_;
    int base = b * (C_ * PLANE_) + rem;  // max index < 2^31

    if ((p4.x & p4.y & p4.z & p4.w) < 0) {
        // all four cells empty -> stream zeros
        const float4 z = make_float4(0.f, 0.f, 0.f, 0.f);
        #pragma unroll 8
        for (int c = 0; c < C_; ++c) {
            *reinterpret_cast<float4*>(out + base + c * PLANE_) = z;
        }
    } else {
        #pragma unroll 4
        for (int c = 0; c < C_; ++c) {
            float4 v;
            v.x = (p4.x >= 0) ? feats[p4.x * C_ + c] : 0.f;
            v.y = (p4.y >= 0) ? feats[p4.y * C_ + c] : 0.f;
            v.z = (p4.z >= 0) ? feats[p4.z * C_ + c] : 0.f;
            v.w = (p4.w >= 0) ? feats[p4.w * C_ + c] : 0.f;
            *reinterpret_cast<float4*>(out + base + c * PLANE_) = v;
        }
    }
}

// ---------------------------------------------------------------------------
// Fallback (only if ws is too small): zero canvas + direct scatter.
// ---------------------------------------------------------------------------
__global__ void zero_out_kernel(float* __restrict__ out, int n4) {
    int t = blockIdx.x * blockDim.x + threadIdx.x;
    int stride = gridDim.x * blockDim.x;
    const float4 z = make_float4(0.f, 0.f, 0.f, 0.f);
    for (int i = t; i < n4; i += stride) {
        reinterpret_cast<float4*>(out)[i] = z;
    }
}

__global__ void direct_scatter_kernel(const float* __restrict__ feats,
                                      const int* __restrict__ coords,
                                      float* __restrict__ out, int P) {
    // one wave-sized group of 64 threads per pillar; lane = channel
    int p = blockIdx.x * (blockDim.x / 64) + (threadIdx.x >> 6);
    int c = threadIdx.x & 63;
    if (p >= P) return;
    int4 co = reinterpret_cast<const int4*>(coords)[p];
    int pos = co.z * NX_ + co.w;
    out[co.x * (C_ * PLANE_) + c * PLANE_ + pos] = feats[p * C_ + c];
}

extern "C" void kernel_launch(void* const* d_in, const int* in_sizes, int n_in,
                              void* d_out, int out_size, void* d_ws, size_t ws_size,
                              hipStream_t stream) {
    const float* feats  = (const float*)d_in[0];
    const int*   coords = (const int*)d_in[1];
    float* out = (float*)d_out;

    const int P = in_sizes[0] / C_;                 // 96000
    const int B = out_size / (C_ * PLANE_);         // 8
    const int ncells = B * PLANE_;                  // 1,714,176
    const size_t ws_needed = (size_t)ncells * sizeof(int);

    if (ws_size >= ws_needed) {
        int* idx = (int*)d_ws;
        int n4 = ncells / 4;
        {
            int blocks = min((n4 + 255) / 256, 2048);
            init_idx_kernel<<<blocks, 256, 0, stream>>>(idx, n4);
        }
        {
            int blocks = (P + 255) / 256;
            scatter_idx_kernel<<<blocks, 256, 0, stream>>>(coords, idx, P);
        }
        {
            int blocks = (n4 + 255) / 256;
            fill_out_kernel<<<blocks, 256, 0, stream>>>(feats, idx, out, n4);
        }
    } else {
        int n4 = out_size / 4;
        {
            int blocks = min((n4 + 255) / 256, 4096);
            zero_out_kernel<<<blocks, 256, 0, stream>>>(out, n4);
        }
        {
            int pillars_per_block = 256 / 64;
            int blocks = (P + pillars_per_block - 1) / pillars_per_block;
            direct_scatter_kernel<<<blocks, 256, 0, stream>>>(feats, coords, out, P);
        }
    }
}

// Round 2
// 172.392 us; speedup vs baseline: 1.5948x; 1.5948x over previous
//
#include <hip/hip_runtime.h>

#define NY_ 496
#define NX_ 432
#define C_  64
#define PLANE_ (NY_ * NX_)   // 214272

// ---------------------------------------------------------------------------
// Pass 1: init index map to -1 (vectorized int4, grid-stride)
// ---------------------------------------------------------------------------
__global__ void init_idx_kernel(int* __restrict__ idx, int n4) {
    int t = blockIdx.x * blockDim.x + threadIdx.x;
    int stride = gridDim.x * blockDim.x;
    const int4 m = make_int4(-1, -1, -1, -1);
    for (int i = t; i < n4; i += stride) {
        reinterpret_cast<int4*>(idx)[i] = m;
    }
}

// ---------------------------------------------------------------------------
// Pass 2: scatter pillar index into the map (tiny: P 4-byte writes)
// coords row = [sample, z, y, x]
// ---------------------------------------------------------------------------
__global__ void scatter_idx_kernel(const int* __restrict__ coords,
                                   int* __restrict__ idx, int P) {
    int p = blockIdx.x * blockDim.x + threadIdx.x;
    if (p >= P) return;
    int4 c = reinterpret_cast<const int4*>(coords)[p];
    int lin = c.x * PLANE_ + c.z * NX_ + c.w;
    idx[lin] = p;
}

// ---------------------------------------------------------------------------
// Pass 3: write the whole canvas, fully coalesced and BRANCHLESS.
// Each thread owns 4 consecutive (y,x) cells. Every lane always loads
// (empty lanes read feats[0..63], a hot broadcast cache line) and multiplies
// by a 0/1 mask, so every float4 store is a full-wave 1 KiB contiguous burst
// under a uniform exec mask — no partial cache lines, no divergence.
// ---------------------------------------------------------------------------
__global__ void fill_out_kernel(const float* __restrict__ feats,
                                const int* __restrict__ idx,
                                float* __restrict__ out, int ncell4) {
    int t = blockIdx.x * blockDim.x + threadIdx.x;
    if (t >= ncell4) return;

    int4 p4 = reinterpret_cast<const int4*>(idx)[t];
    int cell0 = t << 2;                  // PLANE_ % 4 == 0, so 4 cells share a sample
    int b = cell0 / PLANE_;
    int rem = cell0 - b * PLANE_;
    int base = b * (C_ * PLANE_) + rem;  // max 109,707,200 < 2^31

    const float* f0 = feats + ((p4.x < 0) ? 0 : (p4.x * C_));
    const float* f1 = feats + ((p4.y < 0) ? 0 : (p4.y * C_));
    const float* f2 = feats + ((p4.z < 0) ? 0 : (p4.z * C_));
    const float* f3 = feats + ((p4.w < 0) ? 0 : (p4.w * C_));
    const float m0 = (p4.x < 0) ? 0.f : 1.f;
    const float m1 = (p4.y < 0) ? 0.f : 1.f;
    const float m2 = (p4.z < 0) ? 0.f : 1.f;
    const float m3 = (p4.w < 0) ? 0.f : 1.f;

    #pragma unroll 8
    for (int c = 0; c < C_; ++c) {
        float4 v;
        v.x = f0[c] * m0;
        v.y = f1[c] * m1;
        v.z = f2[c] * m2;
        v.w = f3[c] * m3;
        *reinterpret_cast<float4*>(out + base + c * PLANE_) = v;
    }
}

// ---------------------------------------------------------------------------
// Fallback (only if ws is too small): zero canvas + direct scatter.
// ---------------------------------------------------------------------------
__global__ void zero_out_kernel(float* __restrict__ out, int n4) {
    int t = blockIdx.x * blockDim.x + threadIdx.x;
    int stride = gridDim.x * blockDim.x;
    const float4 z = make_float4(0.f, 0.f, 0.f, 0.f);
    for (int i = t; i < n4; i += stride) {
        reinterpret_cast<float4*>(out)[i] = z;
    }
}

__global__ void direct_scatter_kernel(const float* __restrict__ feats,
                                      const int* __restrict__ coords,
                                      float* __restrict__ out, int P) {
    int p = blockIdx.x * (blockDim.x / 64) + (threadIdx.x >> 6);
    int c = threadIdx.x & 63;
    if (p >= P) return;
    int4 co = reinterpret_cast<const int4*>(coords)[p];
    int pos = co.z * NX_ + co.w;
    out[co.x * (C_ * PLANE_) + c * PLANE_ + pos] = feats[p * C_ + c];
}

extern "C" void kernel_launch(void* const* d_in, const int* in_sizes, int n_in,
                              void* d_out, int out_size, void* d_ws, size_t ws_size,
                              hipStream_t stream) {
    const float* feats  = (const float*)d_in[0];
    const int*   coords = (const int*)d_in[1];
    float* out = (float*)d_out;

    const int P = in_sizes[0] / C_;                 // 96000
    const int B = out_size / (C_ * PLANE_);         // 8
    const int ncells = B * PLANE_;                  // 1,714,176
    const size_t ws_needed = (size_t)ncells * sizeof(int);

    if (ws_size >= ws_needed) {
        int* idx = (int*)d_ws;
        int n4 = ncells / 4;
        {
            int blocks = min((n4 + 255) / 256, 2048);
            init_idx_kernel<<<blocks, 256, 0, stream>>>(idx, n4);
        }
        {
            int blocks = (P + 255) / 256;
            scatter_idx_kernel<<<blocks, 256, 0, stream>>>(coords, idx, P);
        }
        {
            int blocks = (n4 + 255) / 256;
            fill_out_kernel<<<blocks, 256, 0, stream>>>(feats, idx, out, n4);
        }
    } else {
        int n4 = out_size / 4;
        {
            int blocks = min((n4 + 255) / 256, 4096);
            zero_out_kernel<<<blocks, 256, 0, stream>>>(out, n4);
        }
        {
            int pillars_per_block = 256 / 64;
            int blocks = (P + pillars_per_block - 1) / pillars_per_block;
            direct_scatter_kernel<<<blocks, 256, 0, stream>>>(feats, coords, out, P);
        }
    }
}

// Round 4
// 95.686 us; speedup vs baseline: 2.8732x; 1.8016x over previous
//
#include <hip/hip_runtime.h>

#define NY_ 496
#define NX_ 432
#define C_  64
#define PLANE_ (NY_ * NX_)   // 214272

typedef float f32x4 __attribute__((ext_vector_type(4)));

// ---------------------------------------------------------------------------
// Pass 1: init index map to -1 (vectorized int4, grid-stride)
// ---------------------------------------------------------------------------
__global__ void init_idx_kernel(int* __restrict__ idx, int n4) {
    int t = blockIdx.x * blockDim.x + threadIdx.x;
    int stride = gridDim.x * blockDim.x;
    const int4 m = make_int4(-1, -1, -1, -1);
    for (int i = t; i < n4; i += stride) {
        reinterpret_cast<int4*>(idx)[i] = m;
    }
}

// ---------------------------------------------------------------------------
// Pass 2: scatter pillar index into the map (tiny: P 4-byte writes)
// coords row = [sample, z, y, x]
// ---------------------------------------------------------------------------
__global__ void scatter_idx_kernel(const int* __restrict__ coords,
                                   int* __restrict__ idx, int P) {
    int p = blockIdx.x * blockDim.x + threadIdx.x;
    if (p >= P) return;
    int4 c = reinterpret_cast<const int4*>(coords)[p];
    int lin = c.x * PLANE_ + c.z * NX_ + c.w;
    idx[lin] = p;
}

// ---------------------------------------------------------------------------
// Pass 3: canvas sweep, branchless, 4x-vectorized gather.
// Each thread owns 4 consecutive (y,x) cells. Per channel-group of 4:
//   - load one float4 from each cell's feats row (16 B contiguous each)
//   - 4x4 in-register transpose -> per-channel float4 across the 4 cells
//   - nontemporal float4 store (full-wave 1 KiB contiguous burst)
// VMEM instrs per thread: 64 loads + 64 stores (vs 256+64 scalar before).
// ---------------------------------------------------------------------------
__global__ void fill_out_kernel(const float* __restrict__ feats,
                                const int* __restrict__ idx,
                                float* __restrict__ out, int ncell4) {
    int t = blockIdx.x * blockDim.x + threadIdx.x;
    if (t >= ncell4) return;

    int4 p4 = reinterpret_cast<const int4*>(idx)[t];
    int cell0 = t << 2;                  // PLANE_ % 4 == 0 -> 4 cells share a sample
    int b = cell0 / PLANE_;
    int rem = cell0 - b * PLANE_;
    int base = b * (C_ * PLANE_) + rem;  // max 109,707,200 < 2^31

    const f32x4* f0 = reinterpret_cast<const f32x4*>(feats + ((p4.x < 0) ? 0 : (p4.x * C_)));
    const f32x4* f1 = reinterpret_cast<const f32x4*>(feats + ((p4.y < 0) ? 0 : (p4.y * C_)));
    const f32x4* f2 = reinterpret_cast<const f32x4*>(feats + ((p4.z < 0) ? 0 : (p4.z * C_)));
    const f32x4* f3 = reinterpret_cast<const f32x4*>(feats + ((p4.w < 0) ? 0 : (p4.w * C_)));
    const float m0 = (p4.x < 0) ? 0.f : 1.f;
    const float m1 = (p4.y < 0) ? 0.f : 1.f;
    const float m2 = (p4.z < 0) ? 0.f : 1.f;
    const float m3 = (p4.w < 0) ? 0.f : 1.f;

    #pragma unroll 4
    for (int cg = 0; cg < C_ / 4; ++cg) {
        f32x4 a0 = f0[cg] * m0;
        f32x4 a1 = f1[cg] * m1;
        f32x4 a2 = f2[cg] * m2;
        f32x4 a3 = f3[cg] * m3;

        float* o = out + base + (cg * 4) * PLANE_;
        f32x4 s0 = {a0.x, a1.x, a2.x, a3.x};
        f32x4 s1 = {a0.y, a1.y, a2.y, a3.y};
        f32x4 s2 = {a0.z, a1.z, a2.z, a3.z};
        f32x4 s3 = {a0.w, a1.w, a2.w, a3.w};
        __builtin_nontemporal_store(s0, reinterpret_cast<f32x4*>(o));
        __builtin_nontemporal_store(s1, reinterpret_cast<f32x4*>(o + PLANE_));
        __builtin_nontemporal_store(s2, reinterpret_cast<f32x4*>(o + 2 * PLANE_));
        __builtin_nontemporal_store(s3, reinterpret_cast<f32x4*>(o + 3 * PLANE_));
    }
}

// ---------------------------------------------------------------------------
// Fallback (only if ws is too small): zero canvas + direct scatter.
// ---------------------------------------------------------------------------
__global__ void zero_out_kernel(float* __restrict__ out, int n4) {
    int t = blockIdx.x * blockDim.x + threadIdx.x;
    int stride = gridDim.x * blockDim.x;
    const float4 z = make_float4(0.f, 0.f, 0.f, 0.f);
    for (int i = t; i < n4; i += stride) {
        reinterpret_cast<float4*>(out)[i] = z;
    }
}

__global__ void direct_scatter_kernel(const float* __restrict__ feats,
                                      const int* __restrict__ coords,
                                      float* __restrict__ out, int P) {
    int p = blockIdx.x * (blockDim.x / 64) + (threadIdx.x >> 6);
    int c = threadIdx.x & 63;
    if (p >= P) return;
    int4 co = reinterpret_cast<const int4*>(coords)[p];
    int pos = co.z * NX_ + co.w;
    out[co.x * (C_ * PLANE_) + c * PLANE_ + pos] = feats[p * C_ + c];
}

extern "C" void kernel_launch(void* const* d_in, const int* in_sizes, int n_in,
                              void* d_out, int out_size, void* d_ws, size_t ws_size,
                              hipStream_t stream) {
    const float* feats  = (const float*)d_in[0];
    const int*   coords = (const int*)d_in[1];
    float* out = (float*)d_out;

    const int P = in_sizes[0] / C_;                 // 96000
    const int B = out_size / (C_ * PLANE_);         // 8
    const int ncells = B * PLANE_;                  // 1,714,176
    const size_t ws_needed = (size_t)ncells * sizeof(int);

    if (ws_size >= ws_needed) {
        int* idx = (int*)d_ws;
        int n4 = ncells / 4;
        {
            int blocks = min((n4 + 255) / 256, 2048);
            init_idx_kernel<<<blocks, 256, 0, stream>>>(idx, n4);
        }
        {
            int blocks = (P + 255) / 256;
            scatter_idx_kernel<<<blocks, 256, 0, stream>>>(coords, idx, P);
        }
        {
            int blocks = (n4 + 255) / 256;
            fill_out_kernel<<<blocks, 256, 0, stream>>>(feats, idx, out, n4);
        }
    } else {
        int n4 = out_size / 4;
        {
            int blocks = min((n4 + 255) / 256, 4096);
            zero_out_kernel<<<blocks, 256, 0, stream>>>(out, n4);
        }
        {
            int pillars_per_block = 256 / 64;
            int blocks = (P + pillars_per_block - 1) / pillars_per_block;
            direct_scatter_kernel<<<blocks, 256, 0, stream>>>(feats, coords, out, P);
        }
    }
}